// Round 3
// baseline (365.610 us; speedup 1.0000x reference)
//
#include <hip/hip_runtime.h>
#include <hip/hip_bf16.h>
#include <math.h>

typedef __attribute__((ext_vector_type(8))) short bf16x8;
typedef __attribute__((ext_vector_type(4))) float f32x4;
typedef unsigned int u32;

__device__ inline ushort f2bf(float x) {
  union { float f; unsigned u; } c; c.f = x;
  unsigned u = c.u;
  u += 0x7fffu + ((u >> 16) & 1u);   // RTNE
  return (ushort)(u >> 16);
}

__device__ __forceinline__ float rcpf(float x) { return __builtin_amdgcn_rcpf(x); }

// async global->LDS, 16B per lane; LDS dest = wave-uniform base + lane*16
__device__ __forceinline__ void gl_lds16(const ushort* g, ushort* l) {
  __builtin_amdgcn_global_load_lds(
      (const __attribute__((address_space(1))) u32*)g,
      (__attribute__((address_space(3))) u32*)l, 16, 0, 0);
}

// ---- fused: adjacency fp32->bf16 + AN (blocks [0,R)) and I fp32->bf16 (rest) ----
__global__ __launch_bounds__(256) void conv_fused(const float* __restrict__ adj,
                                                  const float* __restrict__ Nv,
                                                  const float* __restrict__ I,
                                                  ushort* __restrict__ adjbf,
                                                  ushort* __restrict__ Ibf,
                                                  float* __restrict__ AN,
                                                  int R, int nI) {
  const int bx = blockIdx.x;
  const int tid = threadIdx.x;
  if (bx < R) {
    const int r = bx;
    const float* row = adj + (size_t)r * R;
    ushort* orow = adjbf + (size_t)r * R;
    float acc = 0.f;
    for (int q0 = tid * 4; q0 < R; q0 += 256 * 4) {
      float4 v = *(const float4*)(row + q0);
      float4 nv = *(const float4*)(Nv + q0);
      acc += v.x * nv.x + v.y * nv.y + v.z * nv.z + v.w * nv.w;
      ushort4 o;
      o.x = f2bf(v.x); o.y = f2bf(v.y); o.z = f2bf(v.z); o.w = f2bf(v.w);
      *(ushort4*)(orow + q0) = o;
    }
    #pragma unroll
    for (int off = 32; off > 0; off >>= 1) acc += __shfl_down(acc, off, 64);
    __shared__ float red[4];
    if ((tid & 63) == 0) red[tid >> 6] = acc;
    __syncthreads();
    if (tid == 0) AN[r] = red[0] + red[1] + red[2] + red[3];
  } else {
    int i = ((bx - R) * 256 + tid) * 4;
    if (i + 3 < nI) {
      float4 v = *(const float4*)(I + i);
      ushort4 o;
      o.x = f2bf(v.x); o.y = f2bf(v.y); o.z = f2bf(v.z); o.w = f2bf(v.w);
      *(ushort4*)(Ibf + i) = o;
    }
  }
}

// -------- bf16 MFMA GEMM, global_load_lds staging, XOR-swizzled LDS, split-K --------
// A: [M][K] bf16 row-major, B: [N][K] bf16 row-major; C_z: [M][N] fp32 per split z
__global__ __launch_bounds__(256) void gemm_bt_lds(const ushort* __restrict__ A,
                                                   const ushort* __restrict__ B,
                                                   float* __restrict__ C,
                                                   int M, int N, int K, int Ksplit) {
  __shared__ __align__(16) ushort sA[128 * 32];
  __shared__ __align__(16) ushort sB[128 * 32];
  const int tid = threadIdx.x;
  const int bn = blockIdx.x, bm = blockIdx.y, bz = blockIdx.z;
  const int wave = tid >> 6, lane = tid & 63;
  const int wm = (wave >> 1) * 64, wn = (wave & 1) * 64;   // 2x2 waves, 64x64 each

  const int p0 = wave * 2, p1 = wave * 2 + 1;
  const int lrow = lane >> 2;                        // [0,16)
  const int sblk = (lane & 3) ^ (lrow & 3);          // swizzled col block
  const int scol = sblk * 8;
  const size_t kbase = (size_t)bz * Ksplit + scol;
  const ushort* Ag0 = A + (size_t)(bm * 128 + p0 * 16 + lrow) * K + kbase;
  const ushort* Ag1 = A + (size_t)(bm * 128 + p1 * 16 + lrow) * K + kbase;
  const ushort* Bg0 = B + (size_t)(bn * 128 + p0 * 16 + lrow) * K + kbase;
  const ushort* Bg1 = B + (size_t)(bn * 128 + p1 * 16 + lrow) * K + kbase;
  ushort* sA0 = sA + p0 * 16 * 32;
  ushort* sA1 = sA + p1 * 16 * 32;
  ushort* sB0 = sB + p0 * 16 * 32;
  ushort* sB1 = sB + p1 * 16 * 32;

  const int fm = lane & 15;
  const int fkb = lane >> 4;
  const int pblk = (fkb ^ (fm & 3)) * 8;

  f32x4 acc[4][4];
  #pragma unroll
  for (int i = 0; i < 4; ++i)
    #pragma unroll
    for (int j = 0; j < 4; ++j) acc[i][j] = (f32x4){0.f, 0.f, 0.f, 0.f};

  for (int k0 = 0; k0 < Ksplit; k0 += 32) {
    __syncthreads();
    gl_lds16(Ag0 + k0, sA0);
    gl_lds16(Ag1 + k0, sA1);
    gl_lds16(Bg0 + k0, sB0);
    gl_lds16(Bg1 + k0, sB1);
    __syncthreads();
    bf16x8 af[4], bfr[4];
    #pragma unroll
    for (int i = 0; i < 4; ++i)
      af[i] = *(const bf16x8*)(sA + (wm + i * 16 + fm) * 32 + pblk);
    #pragma unroll
    for (int j = 0; j < 4; ++j)
      bfr[j] = *(const bf16x8*)(sB + (wn + j * 16 + fm) * 32 + pblk);
    #pragma unroll
    for (int i = 0; i < 4; ++i)
      #pragma unroll
      for (int j = 0; j < 4; ++j)
        acc[i][j] = __builtin_amdgcn_mfma_f32_16x16x32_bf16(af[i], bfr[j], acc[i][j], 0, 0, 0);
  }

  float* Cz = C + (size_t)bz * M * N;
  const int cm = (lane >> 4) * 4, cn = lane & 15;
  #pragma unroll
  for (int i = 0; i < 4; ++i)
    #pragma unroll
    for (int j = 0; j < 4; ++j) {
      size_t base = (size_t)(bm * 128 + wm + i * 16 + cm) * N + (bn * 128 + wn + j * 16 + cn);
      #pragma unroll
      for (int v = 0; v < 4; ++v)
        Cz[base + (size_t)v * N] = acc[i][j][v];
    }
}

// ---------------- fused log-prob ----------------
// All divides via v_rcp_f32 (~1 ulp); the 4 per-flow logs fused into one __logf.
__device__ __forceinline__ float elem_ll(float Sv, float Ev, float Iv, float Tv,
                                         float sev, float eiv, float itv, float iuv,
                                         float trv, float tdv, float dev, float rev,
                                         float cov, float aiv, float ran_,
                                         float dE, float omE, float dI, float omI,
                                         float dT, float omT) {
  // S flow, k=1, p = -expm1(-c*AI/AN)
  float p = -expm1f(-(cov * aiv) * ran_);
  float mS = Sv * p;
  float varS = mS * (1.f - p);
  float dS = sev - mS;
  // E flow, k=1
  float mE = Ev * dE;
  float varE = mE * omE;
  float dEd = eiv - mE;
  // I flow, k=2
  float p1 = dev * dI, p2 = (1.f - dev) * dI;
  float d1 = itv - Iv * p1;
  float d2 = iuv - Iv * p2;
  float denI = Iv * p1 * p2 * omI;
  float qI = (d1 * d1 * p2 * (1.f - p2) + 2.f * d1 * d2 * p1 * p2 +
              d2 * d2 * p1 * (1.f - p1)) * rcpf(denI);
  // T flow, k=2
  float q1 = rev * dT, q2 = (1.f - rev) * dT;
  float e1 = trv - Tv * q1;
  float e2 = tdv - Tv * q2;
  float denT = Tv * q1 * q2 * omT;
  float qT = (e1 * e1 * q2 * (1.f - q2) + 2.f * e1 * e2 * q1 * q2 +
              e2 * e2 * q1 * (1.f - q1)) * rcpf(denT);

  float quad = dS * dS * rcpf(varS) + dEd * dEd * rcpf(varE) + qI + qT;
  float lg = __logf((varS * varE) * ((Iv * denI) * (Tv * denT)));
  return lg + quad;
}

// Straight-line dual-t body: 34 independent loads issued before compute so the
// scheduler can keep many in flight. launch_bounds(256,4) -> VGPR cap 128
// (16 waves/CU) to give it register room. Odd tail: B-row aliases A-row
// (in-bounds) and its contribution is multiplied by 0.
template <int NS>
__global__ __launch_bounds__(256, 4) void logprob_kernel(
    const float* __restrict__ S, const float* __restrict__ E,
    const float* __restrict__ I, const float* __restrict__ T,
    const float* __restrict__ S_E, const float* __restrict__ E_I,
    const float* __restrict__ I_T, const float* __restrict__ I_U,
    const float* __restrict__ T_R, const float* __restrict__ T_D,
    const float* __restrict__ detr, const float* __restrict__ recr,
    const float* __restrict__ cont, const float* __restrict__ AI,
    const float* __restrict__ AN,
    const float* __restrict__ pldE, const float* __restrict__ pldI,
    const float* __restrict__ pldT, float* __restrict__ partial, int D1, int R) {
  const int r0 = (blockIdx.x * 256 + threadIdx.x) * 4;
  const size_t sstride = (size_t)(D1 + 1) * R;  // D*R per split
  const float dE = 1.f / (1.f + __expf(-pldE[0]));
  const float dI = 1.f / (1.f + __expf(-pldI[0]));
  const float dT = 1.f / (1.f + __expf(-pldT[0]));
  const float omE = 1.f - dE, omI = 1.f - dI, omT = 1.f - dT;
  const float L2PI = 1.8378770664093453f;
  float4 an4 = *(const float4*)(AN + r0);
  float ran_[4] = {rcpf(an4.x), rcpf(an4.y), rcpf(an4.z), rcpf(an4.w)};

  const int t0 = blockIdx.y * 2;
  const bool two = (t0 + 1 < D1);
  const float wB = two ? 1.f : 0.f;
  const size_t iA = (size_t)t0 * R + r0;
  const size_t iB = iA + (two ? (size_t)R : 0);

#define LD4(arr, i) (*(const float4*)((arr) + (i)))
  // ---- issue all independent loads up front ----
  float4 SvA = LD4(S, iA),   SvB = LD4(S, iB);
  float4 EvA = LD4(E, iA),   EvB = LD4(E, iB);
  float4 IvA = LD4(I, iA),   IvB = LD4(I, iB);
  float4 TvA = LD4(T, iA),   TvB = LD4(T, iB);
  float4 seA = LD4(S_E, iA), seB = LD4(S_E, iB);
  float4 eiA = LD4(E_I, iA), eiB = LD4(E_I, iB);
  float4 itA = LD4(I_T, iA), itB = LD4(I_T, iB);
  float4 iuA = LD4(I_U, iA), iuB = LD4(I_U, iB);
  float4 trA = LD4(T_R, iA), trB = LD4(T_R, iB);
  float4 tdA = LD4(T_D, iA), tdB = LD4(T_D, iB);
  float4 deA = LD4(detr, iA), deB = LD4(detr, iB);
  float4 reA = LD4(recr, iA), reB = LD4(recr, iB);
  float4 coA = LD4(cont, iA), coB = LD4(cont, iB);

  float aiA[4] = {0.f, 0.f, 0.f, 0.f};
  float aiB[4] = {0.f, 0.f, 0.f, 0.f};
  #pragma unroll
  for (int s = 0; s < NS; ++s) {
    float4 a = LD4(AI, s * sstride + iA);
    float4 b = LD4(AI, s * sstride + iB);
    aiA[0] += a.x; aiA[1] += a.y; aiA[2] += a.z; aiA[3] += a.w;
    aiB[0] += b.x; aiB[1] += b.y; aiB[2] += b.z; aiB[3] += b.w;
  }
#undef LD4

  float accA[4], accB[4];
  {
    float Sa[4] = {SvA.x, SvA.y, SvA.z, SvA.w}, Ea[4] = {EvA.x, EvA.y, EvA.z, EvA.w};
    float Ia[4] = {IvA.x, IvA.y, IvA.z, IvA.w}, Ta[4] = {TvA.x, TvA.y, TvA.z, TvA.w};
    float sea[4] = {seA.x, seA.y, seA.z, seA.w}, eia[4] = {eiA.x, eiA.y, eiA.z, eiA.w};
    float ita[4] = {itA.x, itA.y, itA.z, itA.w}, iua[4] = {iuA.x, iuA.y, iuA.z, iuA.w};
    float tra[4] = {trA.x, trA.y, trA.z, trA.w}, tda[4] = {tdA.x, tdA.y, tdA.z, tdA.w};
    float dea[4] = {deA.x, deA.y, deA.z, deA.w}, rea[4] = {reA.x, reA.y, reA.z, reA.w};
    float coa[4] = {coA.x, coA.y, coA.z, coA.w};
    #pragma unroll
    for (int v = 0; v < 4; ++v)
      accA[v] = elem_ll(Sa[v], Ea[v], Ia[v], Ta[v], sea[v], eia[v], ita[v], iua[v],
                        tra[v], tda[v], dea[v], rea[v], coa[v], aiA[v], ran_[v],
                        dE, omE, dI, omI, dT, omT);
  }
  {
    float Sa[4] = {SvB.x, SvB.y, SvB.z, SvB.w}, Ea[4] = {EvB.x, EvB.y, EvB.z, EvB.w};
    float Ia[4] = {IvB.x, IvB.y, IvB.z, IvB.w}, Ta[4] = {TvB.x, TvB.y, TvB.z, TvB.w};
    float sea[4] = {seB.x, seB.y, seB.z, seB.w}, eia[4] = {eiB.x, eiB.y, eiB.z, eiB.w};
    float ita[4] = {itB.x, itB.y, itB.z, itB.w}, iua[4] = {iuB.x, iuB.y, iuB.z, iuB.w};
    float tra[4] = {trB.x, trB.y, trB.z, trB.w}, tda[4] = {tdB.x, tdB.y, tdB.z, tdB.w};
    float dea[4] = {deB.x, deB.y, deB.z, deB.w}, rea[4] = {reB.x, reB.y, reB.z, reB.w};
    float coa[4] = {coB.x, coB.y, coB.z, coB.w};
    #pragma unroll
    for (int v = 0; v < 4; ++v)
      accB[v] = elem_ll(Sa[v], Ea[v], Ia[v], Ta[v], sea[v], eia[v], ita[v], iua[v],
                        tra[v], tda[v], dea[v], rea[v], coa[v], aiB[v], ran_[v],
                        dE, omE, dI, omI, dT, omT);
  }

  const float cterm = -3.f * L2PI * (two ? 2.f : 1.f);
  float4 res;
  res.x = -0.5f * (accA[0] + wB * accB[0]) + cterm;
  res.y = -0.5f * (accA[1] + wB * accB[1]) + cterm;
  res.z = -0.5f * (accA[2] + wB * accB[2]) + cterm;
  res.w = -0.5f * (accA[3] + wB * accB[3]) + cterm;
  *(float4*)(partial + (size_t)blockIdx.y * R + r0) = res;
}

// ---- final reduction: out[r] = sum_by partial[by][r], NBY rows ----
__global__ __launch_bounds__(256) void reduce_kernel(const float* __restrict__ part,
                                                     float* __restrict__ out,
                                                     int R, int NBY) {
  __shared__ float red[256];
  const int tid = threadIdx.x;
  const int r = blockIdx.x * 32 + (tid & 31);
  const int slice = tid >> 5;          // 8 slices over NBY
  const int rows = NBY >> 3;
  float acc = 0.f;
  for (int k = 0; k < rows; ++k)
    acc += part[(size_t)(slice * rows + k) * R + r];
  red[tid] = acc;
  __syncthreads();
  if (tid < 32) {
    float s = red[tid];
    #pragma unroll
    for (int sl = 1; sl < 8; ++sl) s += red[sl * 32 + tid];
    out[r] = s;
  }
}

extern "C" void kernel_launch(void* const* d_in, const int* in_sizes, int n_in,
                              void* d_out, int out_size, void* d_ws, size_t ws_size,
                              hipStream_t stream) {
  const float* S    = (const float*)d_in[0];
  const float* E    = (const float*)d_in[1];
  const float* I    = (const float*)d_in[2];
  const float* T    = (const float*)d_in[3];
  const float* Nv   = (const float*)d_in[4];
  const float* S_E  = (const float*)d_in[5];
  const float* E_I  = (const float*)d_in[6];
  const float* I_T  = (const float*)d_in[7];
  const float* I_U  = (const float*)d_in[8];
  const float* T_R  = (const float*)d_in[9];
  const float* T_D  = (const float*)d_in[10];
  const float* adj  = (const float*)d_in[11];
  const float* ldE  = (const float*)d_in[12];
  const float* ldI  = (const float*)d_in[13];
  const float* ldT  = (const float*)d_in[14];
  const float* detr = (const float*)d_in[15];
  const float* recr = (const float*)d_in[16];
  const float* cont = (const float*)d_in[17];
  float* out = (float*)d_out;

  const int R  = in_sizes[4];       // 4096
  const int D  = in_sizes[0] / R;   // 1024
  const int D1 = D - 1;             // 1023
  const int NBY = (D1 + 1) / 2;     // 512 t-chunks

  // ws: adjbf (R*R bf16) | Ibf (D*R bf16) | AI x NS (D*R f32) | AN (R f32) | partial (NBY*R f32)
  char* ws = (char*)d_ws;
  ushort* adjbf = (ushort*)ws;
  ushort* Ibf   = (ushort*)(ws + (size_t)R * R * 2);
  float*  AIbuf = (float*)(ws + (size_t)R * R * 2 + (size_t)D * R * 2);
  const size_t tail = (size_t)R * 4 + (size_t)NBY * R * 4;
  const size_t need4 = (size_t)R * R * 2 + (size_t)D * R * 2 +
                       4 * (size_t)D * R * 4 + tail;
  const int NS = (ws_size >= need4) ? 4 : 2;
  float* ANbuf   = (float*)((char*)AIbuf + (size_t)NS * D * R * 4);
  float* partial = ANbuf + R;

  const int nI = D * R;
  const int convBlocks = R + nI / (256 * 4);
  hipLaunchKernelGGL(conv_fused, dim3(convBlocks), dim3(256), 0, stream,
                     adj, Nv, I, adjbf, Ibf, ANbuf, R, nI);
  hipLaunchKernelGGL(gemm_bt_lds, dim3(R / 128, D / 128, NS), dim3(256), 0, stream,
                     Ibf, adjbf, AIbuf, D, R, R, R / NS);
  if (NS == 4) {
    hipLaunchKernelGGL(logprob_kernel<4>, dim3(R / 1024, NBY), dim3(256), 0, stream,
                       S, E, I, T, S_E, E_I, I_T, I_U, T_R, T_D, detr, recr, cont,
                       AIbuf, ANbuf, ldE, ldI, ldT, partial, D1, R);
  } else {
    hipLaunchKernelGGL(logprob_kernel<2>, dim3(R / 1024, NBY), dim3(256), 0, stream,
                       S, E, I, T, S_E, E_I, I_T, I_U, T_R, T_D, detr, recr, cont,
                       AIbuf, ANbuf, ldE, ldI, ldT, partial, D1, R);
  }
  hipLaunchKernelGGL(reduce_kernel, dim3(R / 32), dim3(256), 0, stream,
                     partial, out, R, NBY);
}

// Round 4
// 355.288 us; speedup vs baseline: 1.0291x; 1.0291x over previous
//
#include <hip/hip_runtime.h>
#include <hip/hip_bf16.h>
#include <math.h>

typedef __attribute__((ext_vector_type(8))) short bf16x8;
typedef __attribute__((ext_vector_type(4))) float f32x4;
typedef unsigned int u32;

__device__ inline ushort f2bf(float x) {
  union { float f; unsigned u; } c; c.f = x;
  unsigned u = c.u;
  u += 0x7fffu + ((u >> 16) & 1u);   // RTNE
  return (ushort)(u >> 16);
}

__device__ __forceinline__ float rcpf(float x) { return __builtin_amdgcn_rcpf(x); }

// async global->LDS, 16B per lane; LDS dest = wave-uniform base + lane*16
__device__ __forceinline__ void gl_lds16(const ushort* g, ushort* l) {
  __builtin_amdgcn_global_load_lds(
      (const __attribute__((address_space(1))) u32*)g,
      (__attribute__((address_space(3))) u32*)l, 16, 0, 0);
}

// ---- fused: adjacency fp32->bf16 + AN (blocks [0,R)) and I fp32->bf16 (rest) ----
__global__ __launch_bounds__(256) void conv_fused(const float* __restrict__ adj,
                                                  const float* __restrict__ Nv,
                                                  const float* __restrict__ I,
                                                  ushort* __restrict__ adjbf,
                                                  ushort* __restrict__ Ibf,
                                                  float* __restrict__ AN,
                                                  int R, int nI) {
  const int bx = blockIdx.x;
  const int tid = threadIdx.x;
  if (bx < R) {
    const int r = bx;
    const float* row = adj + (size_t)r * R;
    ushort* orow = adjbf + (size_t)r * R;
    float acc = 0.f;
    for (int q0 = tid * 4; q0 < R; q0 += 256 * 4) {
      float4 v = *(const float4*)(row + q0);
      float4 nv = *(const float4*)(Nv + q0);
      acc += v.x * nv.x + v.y * nv.y + v.z * nv.z + v.w * nv.w;
      ushort4 o;
      o.x = f2bf(v.x); o.y = f2bf(v.y); o.z = f2bf(v.z); o.w = f2bf(v.w);
      *(ushort4*)(orow + q0) = o;
    }
    #pragma unroll
    for (int off = 32; off > 0; off >>= 1) acc += __shfl_down(acc, off, 64);
    __shared__ float red[4];
    if ((tid & 63) == 0) red[tid >> 6] = acc;
    __syncthreads();
    if (tid == 0) AN[r] = red[0] + red[1] + red[2] + red[3];
  } else {
    int i = ((bx - R) * 256 + tid) * 4;
    if (i + 3 < nI) {
      float4 v = *(const float4*)(I + i);
      ushort4 o;
      o.x = f2bf(v.x); o.y = f2bf(v.y); o.z = f2bf(v.z); o.w = f2bf(v.w);
      *(ushort4*)(Ibf + i) = o;
    }
  }
}

// -------- bf16 MFMA GEMM, 2-phase double-buffered global_load_lds, split-K --------
// A: [M][K] bf16 row-major, B: [N][K] bf16 row-major; C_z: [M][N] fp32 per split z
// T3-minimum schedule: STAGE(next tile) issued BEFORE compute(current), one
// __syncthreads per K-step (drains vmcnt for the staged tile + fences LDS reuse).
__global__ __launch_bounds__(256) void gemm_bt_lds(const ushort* __restrict__ A,
                                                   const ushort* __restrict__ B,
                                                   float* __restrict__ C,
                                                   int M, int N, int K, int Ksplit) {
  __shared__ __align__(16) ushort sA[2][128 * 32];
  __shared__ __align__(16) ushort sB[2][128 * 32];
  const int tid = threadIdx.x;
  const int bn = blockIdx.x, bm = blockIdx.y, bz = blockIdx.z;
  const int wave = tid >> 6, lane = tid & 63;
  const int wm = (wave >> 1) * 64, wn = (wave & 1) * 64;   // 2x2 waves, 64x64 each

  const int p0 = wave * 2, p1 = wave * 2 + 1;
  const int lrow = lane >> 2;                        // [0,16)
  const int sblk = (lane & 3) ^ (lrow & 3);          // swizzled col block
  const int scol = sblk * 8;
  const size_t kbase = (size_t)bz * Ksplit + scol;
  const ushort* Ag0 = A + (size_t)(bm * 128 + p0 * 16 + lrow) * K + kbase;
  const ushort* Ag1 = A + (size_t)(bm * 128 + p1 * 16 + lrow) * K + kbase;
  const ushort* Bg0 = B + (size_t)(bn * 128 + p0 * 16 + lrow) * K + kbase;
  const ushort* Bg1 = B + (size_t)(bn * 128 + p1 * 16 + lrow) * K + kbase;
  const int lo0 = p0 * 16 * 32;     // wave-uniform LDS sub-tile offsets
  const int lo1 = p1 * 16 * 32;

  const int fm = lane & 15;
  const int fkb = lane >> 4;
  const int pblk = (fkb ^ (fm & 3)) * 8;

  f32x4 acc[4][4];
  #pragma unroll
  for (int i = 0; i < 4; ++i)
    #pragma unroll
    for (int j = 0; j < 4; ++j) acc[i][j] = (f32x4){0.f, 0.f, 0.f, 0.f};

  auto STAGE = [&](int b, int k0) {
    gl_lds16(Ag0 + k0, sA[b] + lo0);
    gl_lds16(Ag1 + k0, sA[b] + lo1);
    gl_lds16(Bg0 + k0, sB[b] + lo0);
    gl_lds16(Bg1 + k0, sB[b] + lo1);
  };
  auto COMPUTE = [&](int b) {
    bf16x8 af[4], bfr[4];
    #pragma unroll
    for (int i = 0; i < 4; ++i)
      af[i] = *(const bf16x8*)(sA[b] + (wm + i * 16 + fm) * 32 + pblk);
    #pragma unroll
    for (int j = 0; j < 4; ++j)
      bfr[j] = *(const bf16x8*)(sB[b] + (wn + j * 16 + fm) * 32 + pblk);
    #pragma unroll
    for (int i = 0; i < 4; ++i)
      #pragma unroll
      for (int j = 0; j < 4; ++j)
        acc[i][j] = __builtin_amdgcn_mfma_f32_16x16x32_bf16(af[i], bfr[j], acc[i][j], 0, 0, 0);
  };

  STAGE(0, 0);
  __syncthreads();                     // drain prologue stage
  int cur = 0;
  for (int k0 = 0; k0 + 32 < Ksplit; k0 += 32) {
    STAGE(cur ^ 1, k0 + 32);           // next tile in flight under compute
    COMPUTE(cur);
    __syncthreads();                   // vmcnt drain + LDS reuse fence (1/iter)
    cur ^= 1;
  }
  COMPUTE(cur);                        // last tile

  float* Cz = C + (size_t)bz * M * N;
  const int cm = (lane >> 4) * 4, cn = lane & 15;
  #pragma unroll
  for (int i = 0; i < 4; ++i)
    #pragma unroll
    for (int j = 0; j < 4; ++j) {
      size_t base = (size_t)(bm * 128 + wm + i * 16 + cm) * N + (bn * 128 + wn + j * 16 + cn);
      #pragma unroll
      for (int v = 0; v < 4; ++v)
        Cz[base + (size_t)v * N] = acc[i][j][v];
    }
}

// ---------------- fused log-prob ----------------
// All divides via v_rcp_f32 (~1 ulp); the 4 per-flow logs fused into one __logf.
__device__ __forceinline__ float elem_ll(float Sv, float Ev, float Iv, float Tv,
                                         float sev, float eiv, float itv, float iuv,
                                         float trv, float tdv, float dev, float rev,
                                         float cov, float aiv, float ran_,
                                         float dE, float omE, float dI, float omI,
                                         float dT, float omT) {
  // S flow, k=1, p = -expm1(-c*AI/AN)
  float p = -expm1f(-(cov * aiv) * ran_);
  float mS = Sv * p;
  float varS = mS * (1.f - p);
  float dS = sev - mS;
  // E flow, k=1
  float mE = Ev * dE;
  float varE = mE * omE;
  float dEd = eiv - mE;
  // I flow, k=2
  float p1 = dev * dI, p2 = (1.f - dev) * dI;
  float d1 = itv - Iv * p1;
  float d2 = iuv - Iv * p2;
  float denI = Iv * p1 * p2 * omI;
  float qI = (d1 * d1 * p2 * (1.f - p2) + 2.f * d1 * d2 * p1 * p2 +
              d2 * d2 * p1 * (1.f - p1)) * rcpf(denI);
  // T flow, k=2
  float q1 = rev * dT, q2 = (1.f - rev) * dT;
  float e1 = trv - Tv * q1;
  float e2 = tdv - Tv * q2;
  float denT = Tv * q1 * q2 * omT;
  float qT = (e1 * e1 * q2 * (1.f - q2) + 2.f * e1 * e2 * q1 * q2 +
              e2 * e2 * q1 * (1.f - q1)) * rcpf(denT);

  float quad = dS * dS * rcpf(varS) + dEd * dEd * rcpf(varE) + qI + qT;
  float lg = __logf((varS * varE) * ((Iv * denI) * (Tv * denT)));
  return lg + quad;
}

// Straight-line dual-t body: loads issued up front. Odd tail: B-row aliases
// A-row (in-bounds) and its contribution is multiplied by 0.
template <int NS>
__global__ __launch_bounds__(256, 4) void logprob_kernel(
    const float* __restrict__ S, const float* __restrict__ E,
    const float* __restrict__ I, const float* __restrict__ T,
    const float* __restrict__ S_E, const float* __restrict__ E_I,
    const float* __restrict__ I_T, const float* __restrict__ I_U,
    const float* __restrict__ T_R, const float* __restrict__ T_D,
    const float* __restrict__ detr, const float* __restrict__ recr,
    const float* __restrict__ cont, const float* __restrict__ AI,
    const float* __restrict__ AN,
    const float* __restrict__ pldE, const float* __restrict__ pldI,
    const float* __restrict__ pldT, float* __restrict__ partial, int D1, int R) {
  const int r0 = (blockIdx.x * 256 + threadIdx.x) * 4;
  const size_t sstride = (size_t)(D1 + 1) * R;  // D*R per split
  const float dE = 1.f / (1.f + __expf(-pldE[0]));
  const float dI = 1.f / (1.f + __expf(-pldI[0]));
  const float dT = 1.f / (1.f + __expf(-pldT[0]));
  const float omE = 1.f - dE, omI = 1.f - dI, omT = 1.f - dT;
  const float L2PI = 1.8378770664093453f;
  float4 an4 = *(const float4*)(AN + r0);
  float ran_[4] = {rcpf(an4.x), rcpf(an4.y), rcpf(an4.z), rcpf(an4.w)};

  const int t0 = blockIdx.y * 2;
  const bool two = (t0 + 1 < D1);
  const float wB = two ? 1.f : 0.f;
  const size_t iA = (size_t)t0 * R + r0;
  const size_t iB = iA + (two ? (size_t)R : 0);

#define LD4(arr, i) (*(const float4*)((arr) + (i)))
  // ---- issue all independent loads up front ----
  float4 SvA = LD4(S, iA),   SvB = LD4(S, iB);
  float4 EvA = LD4(E, iA),   EvB = LD4(E, iB);
  float4 IvA = LD4(I, iA),   IvB = LD4(I, iB);
  float4 TvA = LD4(T, iA),   TvB = LD4(T, iB);
  float4 seA = LD4(S_E, iA), seB = LD4(S_E, iB);
  float4 eiA = LD4(E_I, iA), eiB = LD4(E_I, iB);
  float4 itA = LD4(I_T, iA), itB = LD4(I_T, iB);
  float4 iuA = LD4(I_U, iA), iuB = LD4(I_U, iB);
  float4 trA = LD4(T_R, iA), trB = LD4(T_R, iB);
  float4 tdA = LD4(T_D, iA), tdB = LD4(T_D, iB);
  float4 deA = LD4(detr, iA), deB = LD4(detr, iB);
  float4 reA = LD4(recr, iA), reB = LD4(recr, iB);
  float4 coA = LD4(cont, iA), coB = LD4(cont, iB);

  float aiA[4] = {0.f, 0.f, 0.f, 0.f};
  float aiB[4] = {0.f, 0.f, 0.f, 0.f};
  #pragma unroll
  for (int s = 0; s < NS; ++s) {
    float4 a = LD4(AI, s * sstride + iA);
    float4 b = LD4(AI, s * sstride + iB);
    aiA[0] += a.x; aiA[1] += a.y; aiA[2] += a.z; aiA[3] += a.w;
    aiB[0] += b.x; aiB[1] += b.y; aiB[2] += b.z; aiB[3] += b.w;
  }
#undef LD4

  float accA[4], accB[4];
  {
    float Sa[4] = {SvA.x, SvA.y, SvA.z, SvA.w}, Ea[4] = {EvA.x, EvA.y, EvA.z, EvA.w};
    float Ia[4] = {IvA.x, IvA.y, IvA.z, IvA.w}, Ta[4] = {TvA.x, TvA.y, TvA.z, TvA.w};
    float sea[4] = {seA.x, seA.y, seA.z, seA.w}, eia[4] = {eiA.x, eiA.y, eiA.z, eiA.w};
    float ita[4] = {itA.x, itA.y, itA.z, itA.w}, iua[4] = {iuA.x, iuA.y, iuA.z, iuA.w};
    float tra[4] = {trA.x, trA.y, trA.z, trA.w}, tda[4] = {tdA.x, tdA.y, tdA.z, tdA.w};
    float dea[4] = {deA.x, deA.y, deA.z, deA.w}, rea[4] = {reA.x, reA.y, reA.z, reA.w};
    float coa[4] = {coA.x, coA.y, coA.z, coA.w};
    #pragma unroll
    for (int v = 0; v < 4; ++v)
      accA[v] = elem_ll(Sa[v], Ea[v], Ia[v], Ta[v], sea[v], eia[v], ita[v], iua[v],
                        tra[v], tda[v], dea[v], rea[v], coa[v], aiA[v], ran_[v],
                        dE, omE, dI, omI, dT, omT);
  }
  {
    float Sa[4] = {SvB.x, SvB.y, SvB.z, SvB.w}, Ea[4] = {EvB.x, EvB.y, EvB.z, EvB.w};
    float Ia[4] = {IvB.x, IvB.y, IvB.z, IvB.w}, Ta[4] = {TvB.x, TvB.y, TvB.z, TvB.w};
    float sea[4] = {seB.x, seB.y, seB.z, seB.w}, eia[4] = {eiB.x, eiB.y, eiB.z, eiB.w};
    float ita[4] = {itB.x, itB.y, itB.z, itB.w}, iua[4] = {iuB.x, iuB.y, iuB.z, iuB.w};
    float tra[4] = {trB.x, trB.y, trB.z, trB.w}, tda[4] = {tdB.x, tdB.y, tdB.z, tdB.w};
    float dea[4] = {deB.x, deB.y, deB.z, deB.w}, rea[4] = {reB.x, reB.y, reB.z, reB.w};
    float coa[4] = {coB.x, coB.y, coB.z, coB.w};
    #pragma unroll
    for (int v = 0; v < 4; ++v)
      accB[v] = elem_ll(Sa[v], Ea[v], Ia[v], Ta[v], sea[v], eia[v], ita[v], iua[v],
                        tra[v], tda[v], dea[v], rea[v], coa[v], aiB[v], ran_[v],
                        dE, omE, dI, omI, dT, omT);
  }

  const float cterm = -3.f * L2PI * (two ? 2.f : 1.f);
  float4 res;
  res.x = -0.5f * (accA[0] + wB * accB[0]) + cterm;
  res.y = -0.5f * (accA[1] + wB * accB[1]) + cterm;
  res.z = -0.5f * (accA[2] + wB * accB[2]) + cterm;
  res.w = -0.5f * (accA[3] + wB * accB[3]) + cterm;
  *(float4*)(partial + (size_t)blockIdx.y * R + r0) = res;
}

// ---- final reduction: out[r] = sum_by partial[by][r], NBY rows ----
__global__ __launch_bounds__(256) void reduce_kernel(const float* __restrict__ part,
                                                     float* __restrict__ out,
                                                     int R, int NBY) {
  __shared__ float red[256];
  const int tid = threadIdx.x;
  const int r = blockIdx.x * 32 + (tid & 31);
  const int slice = tid >> 5;          // 8 slices over NBY
  const int rows = NBY >> 3;
  float acc = 0.f;
  for (int k = 0; k < rows; ++k)
    acc += part[(size_t)(slice * rows + k) * R + r];
  red[tid] = acc;
  __syncthreads();
  if (tid < 32) {
    float s = red[tid];
    #pragma unroll
    for (int sl = 1; sl < 8; ++sl) s += red[sl * 32 + tid];
    out[r] = s;
  }
}

extern "C" void kernel_launch(void* const* d_in, const int* in_sizes, int n_in,
                              void* d_out, int out_size, void* d_ws, size_t ws_size,
                              hipStream_t stream) {
  const float* S    = (const float*)d_in[0];
  const float* E    = (const float*)d_in[1];
  const float* I    = (const float*)d_in[2];
  const float* T    = (const float*)d_in[3];
  const float* Nv   = (const float*)d_in[4];
  const float* S_E  = (const float*)d_in[5];
  const float* E_I  = (const float*)d_in[6];
  const float* I_T  = (const float*)d_in[7];
  const float* I_U  = (const float*)d_in[8];
  const float* T_R  = (const float*)d_in[9];
  const float* T_D  = (const float*)d_in[10];
  const float* adj  = (const float*)d_in[11];
  const float* ldE  = (const float*)d_in[12];
  const float* ldI  = (const float*)d_in[13];
  const float* ldT  = (const float*)d_in[14];
  const float* detr = (const float*)d_in[15];
  const float* recr = (const float*)d_in[16];
  const float* cont = (const float*)d_in[17];
  float* out = (float*)d_out;

  const int R  = in_sizes[4];       // 4096
  const int D  = in_sizes[0] / R;   // 1024
  const int D1 = D - 1;             // 1023
  const int NBY = (D1 + 1) / 2;     // 512 t-chunks

  // ws: adjbf (R*R bf16) | Ibf (D*R bf16) | AI x NS (D*R f32) | AN (R f32) | partial (NBY*R f32)
  char* ws = (char*)d_ws;
  ushort* adjbf = (ushort*)ws;
  ushort* Ibf   = (ushort*)(ws + (size_t)R * R * 2);
  float*  AIbuf = (float*)(ws + (size_t)R * R * 2 + (size_t)D * R * 2);
  const size_t tail = (size_t)R * 4 + (size_t)NBY * R * 4;
  const size_t need4 = (size_t)R * R * 2 + (size_t)D * R * 2 +
                       4 * (size_t)D * R * 4 + tail;
  const int NS = (ws_size >= need4) ? 4 : 2;
  float* ANbuf   = (float*)((char*)AIbuf + (size_t)NS * D * R * 4);
  float* partial = ANbuf + R;

  const int nI = D * R;
  const int convBlocks = R + nI / (256 * 4);
  hipLaunchKernelGGL(conv_fused, dim3(convBlocks), dim3(256), 0, stream,
                     adj, Nv, I, adjbf, Ibf, ANbuf, R, nI);
  hipLaunchKernelGGL(gemm_bt_lds, dim3(R / 128, D / 128, NS), dim3(256), 0, stream,
                     Ibf, adjbf, AIbuf, D, R, R, R / NS);
  if (NS == 4) {
    hipLaunchKernelGGL(logprob_kernel<4>, dim3(R / 1024, NBY), dim3(256), 0, stream,
                       S, E, I, T, S_E, E_I, I_T, I_U, T_R, T_D, detr, recr, cont,
                       AIbuf, ANbuf, ldE, ldI, ldT, partial, D1, R);
  } else {
    hipLaunchKernelGGL(logprob_kernel<2>, dim3(R / 1024, NBY), dim3(256), 0, stream,
                       S, E, I, T, S_E, E_I, I_T, I_U, T_R, T_D, detr, recr, cont,
                       AIbuf, ANbuf, ldE, ldI, ldT, partial, D1, R);
  }
  hipLaunchKernelGGL(reduce_kernel, dim3(R / 32), dim3(256), 0, stream,
                     partial, out, R, NBY);
}